// Round 8
// baseline (331.774 us; speedup 1.0000x reference)
//
#include <hip/hip_runtime.h>
#include <hip/hip_bf16.h>

#define NN 32768   // nodes
#define BB 64      // graphs
#define MM 512     // nodes per graph
#define HH 4       // heads
#define DD 64      // head dim
#define INF 256    // input features
#define HD 256     // H*D
#define EE 524288  // edges

typedef unsigned short ushort;
typedef unsigned int uint;
typedef short s16x8 __attribute__((ext_vector_type(8)));
typedef ushort u16x8 __attribute__((ext_vector_type(8)));
typedef float f32x4 __attribute__((ext_vector_type(4)));

__device__ __forceinline__ ushort f2bf(float f) {
    uint u = __float_as_uint(f);
    return (ushort)((u + 0x7fffu + ((u >> 16) & 1u)) >> 16);
}
__device__ __forceinline__ float bf2f(ushort u) {
    return __uint_as_float((uint)u << 16);
}
// packed fp32x2 -> bf16x2 (v_cvt_pk_bf16_f32), RNE
__device__ __forceinline__ uint pkbf(float x, float y) {
    __hip_bfloat162 h = __float22bfloat162_rn(make_float2(x, y));
    return *(uint*)&h;
}

// ---------------------------------------------------------------------------
// Convert 3 weight matrices [K=256][N=256] fp32 -> transposed bf16 [N][K].
// ---------------------------------------------------------------------------
__global__ __launch_bounds__(256) void convert_w(
    const float* __restrict__ Wq, const float* __restrict__ Wk,
    const float* __restrict__ Wv, ushort* __restrict__ WT)
{
    const int id = blockIdx.x * 256 + threadIdx.x;   // 3*65536 total
    const int mat = id >> 16, rem = id & 65535;
    const int n = rem >> 8, kk = rem & 255;
    const float* W = (mat == 0) ? Wq : (mat == 1) ? Wk : Wv;
    WT[id] = f2bf(W[kk * 256 + n]);  // WT[mat][n][kk]
}

// ---------------------------------------------------------------------------
// Barrier-free bf16 MFMA GEMM. Within a block, A-rows and B-cols are
// wave-partitioned (2x2 of 64x64) and each fragment is consumed exactly
// once per wave -> no LDS, no __syncthreads in the K-loop. Waves load
// fragments directly from global (A: 128B/row segments; B: 64B/col; L2
// catches the 2x intra-block A reuse under the XCD swizzle). fp32 A is
// cast in-register via v_cvt_pk_bf16_f32. 1-deep manual prefetch.
// ---------------------------------------------------------------------------
__global__ __launch_bounds__(256) void qkv_gemm(
    const float* __restrict__ Xq, const float* __restrict__ Xs,
    const ushort* __restrict__ WT,
    const float* __restrict__ bq, const float* __restrict__ bk,
    const float* __restrict__ bv,
    ushort* __restrict__ qo, ushort* __restrict__ ko, ushort* __restrict__ vo,
    float* __restrict__ sumsq)
{
    __shared__ float wred[4];

    const int id = blockIdx.x;
    const int vv = (id & 7) * 192 + (id >> 3);   // XCD-contiguous row-groups
    const int rt = vv / 6, ct = vv % 6;
    const int wsel = ct >> 1;                    // 0:q 1:k 2:v
    const float* A    = (wsel == 0) ? Xq : Xs;
    const ushort* W   = WT + (size_t)wsel * 65536;
    const float* bias = (wsel == 0) ? bq : (wsel == 1) ? bk : bv;
    ushort* C         = (wsel == 0) ? qo : (wsel == 1) ? ko : vo;
    const int row0 = rt * 128;
    const int col0 = (ct & 1) * 128;

    const int t = threadIdx.x;
    const int l = t & 63, w = t >> 6;
    const int fr = l & 15, q4 = l >> 4;
    const int wr = (w & 1) * 64, wc = (w >> 1) * 64;

    const float* aptr[4];
    const ushort* bptr[4];
#pragma unroll
    for (int i = 0; i < 4; ++i)
        aptr[i] = &A[(size_t)(row0 + wr + i * 16 + fr) * INF + q4 * 8];
#pragma unroll
    for (int j = 0; j < 4; ++j)
        bptr[j] = &W[(size_t)(col0 + wc + j * 16 + fr) * INF + q4 * 8];

    f32x4 acc[4][4] = {};
    float4 apf[4][2];
    u16x8  bpf[4];
#pragma unroll
    for (int i = 0; i < 4; ++i) {
        apf[i][0] = *(const float4*)(aptr[i]);
        apf[i][1] = *(const float4*)(aptr[i] + 4);
    }
#pragma unroll
    for (int j = 0; j < 4; ++j) bpf[j] = *(const u16x8*)(bptr[j]);

    for (int it = 0; it < 8; ++it) {
        // consume prefetch into current fragments
        float4 acur[4][2];
        u16x8  bcur[4];
#pragma unroll
        for (int i = 0; i < 4; ++i) { acur[i][0] = apf[i][0]; acur[i][1] = apf[i][1]; }
#pragma unroll
        for (int j = 0; j < 4; ++j) bcur[j] = bpf[j];

        if (it < 7) {   // issue next-iter loads; they drain during the MFMAs
            const int ko2 = (it + 1) * 32;
#pragma unroll
            for (int i = 0; i < 4; ++i) {
                apf[i][0] = *(const float4*)(aptr[i] + ko2);
                apf[i][1] = *(const float4*)(aptr[i] + ko2 + 4);
            }
#pragma unroll
            for (int j = 0; j < 4; ++j) bpf[j] = *(const u16x8*)(bptr[j] + ko2);
        }

        s16x8 af[4];
#pragma unroll
        for (int i = 0; i < 4; ++i) {
            uint u0 = pkbf(acur[i][0].x, acur[i][0].y);
            uint u1 = pkbf(acur[i][0].z, acur[i][0].w);
            uint u2 = pkbf(acur[i][1].x, acur[i][1].y);
            uint u3 = pkbf(acur[i][1].z, acur[i][1].w);
            uint4 pk = make_uint4(u0, u1, u2, u3);
            af[i] = *(s16x8*)&pk;
        }
#pragma unroll
        for (int i = 0; i < 4; ++i)
#pragma unroll
            for (int j = 0; j < 4; ++j)
                acc[i][j] = __builtin_amdgcn_mfma_f32_16x16x32_bf16(
                    af[i], *(s16x8*)&bcur[j], acc[i][j], 0, 0, 0);
    }

    // epilogue: bias + sumsq + direct bf16 stores
    float loc = 0.f;
#pragma unroll
    for (int j = 0; j < 4; ++j) {
        const int colg = col0 + wc + j * 16 + fr;
        const float bj = bias[colg];
#pragma unroll
        for (int i = 0; i < 4; ++i) {
            const int rowg = row0 + wr + i * 16 + q4 * 4;
#pragma unroll
            for (int m = 0; m < 4; ++m) {
                float cv = acc[i][j][m] + bj;
                loc += cv * cv;
                C[(size_t)(rowg + m) * HD + colg] = f2bf(cv);
            }
        }
    }
    if (wsel < 2) {
#pragma unroll
        for (int off = 32; off > 0; off >>= 1) loc += __shfl_down(loc, off, 64);
        if (l == 0) wred[w] = loc;
        __syncthreads();
        if (t == 0) atomicAdd(&sumsq[wsel], wred[0] + wred[1] + wred[2] + wred[3]);
    }
}

// ---------------------------------------------------------------------------
// kv via MFMA from bf16 k,v. Block = (h, b, z): m-range [z*128, +128).
// 2x2 wave partition. kv parts now stored TRANSPOSED [dv][dk] (f32x4
// stores — C-frag m runs along dk) for attn's B-operand layout.
// ---------------------------------------------------------------------------
#define KVP 136
__global__ __launch_bounds__(256) void kv_mfma(
    const ushort* __restrict__ k16, const ushort* __restrict__ v16,
    float* __restrict__ kv_p, float* __restrict__ ksum_p, float* __restrict__ vsum_p)
{
    const int h = blockIdx.x, b = blockIdx.y, z = blockIdx.z;
    __shared__ ushort kT[64 * KVP];
    __shared__ ushort vT[64 * KVP];
    const int t = threadIdx.x;
    const int l = t & 63, w = t >> 6;
    const size_t base = (size_t)b * MM * HD + (size_t)h * DD;
    const int m0 = z * 128;

    {
        const int mat = t >> 7;
        const int u = t & 63;
        const int dhalf = (t >> 6) & 1;
        const int r0 = 2 * u;
        const int d0 = dhalf * 32;
        const ushort* src = mat ? v16 : k16;
        ushort* dst = mat ? vT : kT;
        const ushort* p0 = &src[base + (size_t)(m0 + r0) * HD + d0];
        const ushort* p1 = p0 + HD;
        u16x8 ra[4], rb[4];
#pragma unroll
        for (int i = 0; i < 4; ++i) ra[i] = *(const u16x8*)(p0 + 8 * i);
#pragma unroll
        for (int i = 0; i < 4; ++i) rb[i] = *(const u16x8*)(p1 + 8 * i);
#pragma unroll
        for (int i = 0; i < 4; ++i)
#pragma unroll
            for (int jj = 0; jj < 8; ++jj) {
                const int d = d0 + 8 * i + jj;
                uint pk = (uint)ra[i][jj] | ((uint)rb[i][jj] << 16);
                *(uint*)&dst[d * KVP + r0] = pk;
            }
    }
    __syncthreads();

    const int fr = l & 15, q4 = l >> 4, kg = q4 * 8;
    const int wr2 = (w & 1) * 32, wc2 = (w >> 1) * 32;
    s16x8 ones;
#pragma unroll
    for (int i = 0; i < 8; ++i) ones[i] = (short)0x3F80;

    f32x4 acc[2][2] = {};
    f32x4 aks[2] = {};
    f32x4 avs[2] = {};
#pragma unroll
    for (int s = 0; s < 4; ++s) {
        const int mo = s * 32 + kg;
        s16x8 af[2], bf[2];
        af[0] = *(const s16x8*)&kT[(wr2 + fr) * KVP + mo];
        af[1] = *(const s16x8*)&kT[(wr2 + 16 + fr) * KVP + mo];
        bf[0] = *(const s16x8*)&vT[(wc2 + fr) * KVP + mo];
        bf[1] = *(const s16x8*)&vT[(wc2 + 16 + fr) * KVP + mo];
#pragma unroll
        for (int il = 0; il < 2; ++il)
#pragma unroll
            for (int jl = 0; jl < 2; ++jl)
                acc[il][jl] = __builtin_amdgcn_mfma_f32_16x16x32_bf16(
                    af[il], bf[jl], acc[il][jl], 0, 0, 0);
#pragma unroll
        for (int il = 0; il < 2; ++il)
            aks[il] = __builtin_amdgcn_mfma_f32_16x16x32_bf16(
                af[il], ones, aks[il], 0, 0, 0);
#pragma unroll
        for (int jl = 0; jl < 2; ++jl)
            avs[jl] = __builtin_amdgcn_mfma_f32_16x16x32_bf16(
                ones, bf[jl], avs[jl], 0, 0, 0);
    }

    // transposed store: kv_p[dv][dk]; C-frag rows are dk, cols (fr) are dv
    float* kvb = &kv_p[(((size_t)b * HH + h) * 4 + z) * 4096];
#pragma unroll
    for (int jl = 0; jl < 2; ++jl) {
        const int dv = wc2 + 16 * jl + fr;
#pragma unroll
        for (int il = 0; il < 2; ++il) {
            const int dk = wr2 + 16 * il + q4 * 4;
            *(f32x4*)&kvb[(size_t)dv * 64 + dk] = acc[il][jl];
        }
    }
    float* ksb = &ksum_p[(((size_t)b * HH + h) * 4 + z) * 64];
    float* vsb = &vsum_p[(((size_t)b * HH + h) * 4 + z) * 64];
    if (wc2 == 0 && fr == 0) {
#pragma unroll
        for (int il = 0; il < 2; ++il)
#pragma unroll
            for (int m = 0; m < 4; ++m)
                ksb[wr2 + 16 * il + q4 * 4 + m] = aks[il][m];
    }
    if (wr2 == 0 && l < 16) {
        vsb[wc2 + l]      = avs[0][0];
        vsb[wc2 + 16 + l] = avs[1][0];
    }
}

// ---------------------------------------------------------------------------
__global__ __launch_bounds__(256) void vbar_kernel(
    const ushort* __restrict__ v16, float* __restrict__ vbar)
{
    const int idx = blockIdx.x * 256 + threadIdx.x;
    const int n = idx >> 6, d = idx & 63;
    const ushort* vr = &v16[(size_t)n * HD + d];
    vbar[idx] = 0.25f * (bf2f(vr[0]) + bf2f(vr[64]) + bf2f(vr[128]) + bf2f(vr[192]));
}

// ---------------------------------------------------------------------------
__global__ __launch_bounds__(256) void deg_kernel(
    const int* __restrict__ ei, int* __restrict__ deg)
{
    const int e = blockIdx.x * 256 + threadIdx.x;
    if (e < EE) atomicAdd(&deg[ei[EE + e]], 1);
}

// ---------------------------------------------------------------------------
__global__ __launch_bounds__(1024) void scan_kernel(
    const int* __restrict__ deg, int* __restrict__ offsets)
{
    __shared__ int part[1024];
    const int tid = threadIdx.x;
    const int base = tid * 32;
    int loc[32];
    int s = 0;
#pragma unroll
    for (int i = 0; i < 32; ++i) { loc[i] = s; s += deg[base + i]; }
    part[tid] = s;
    __syncthreads();
    for (int off = 1; off < 1024; off <<= 1) {
        int a = part[tid];
        int b2 = (tid >= off) ? part[tid - off] : 0;
        __syncthreads();
        part[tid] = a + b2;
        __syncthreads();
    }
    const int prev = (tid == 0) ? 0 : part[tid - 1];
#pragma unroll
    for (int i = 0; i < 32; ++i) offsets[base + i] = prev + loc[i];
    if (tid == 1023) offsets[NN] = prev + s;
}

// ---------------------------------------------------------------------------
__global__ __launch_bounds__(256) void bucket_kernel(
    const int* __restrict__ ei, const float* __restrict__ ew,
    const int* __restrict__ deg, const int* __restrict__ offsets,
    int* __restrict__ cursor, int* __restrict__ rowbuf, float* __restrict__ valbuf)
{
    const int e = blockIdx.x * 256 + threadIdx.x;
    if (e >= EE) return;
    const int row = ei[e], col = ei[EE + e];
    const long long prod = (long long)deg[row] * (long long)deg[col];
    float val = 0.f;
    if (prod > 0) val = ew[e] * __frsqrt_rn((float)prod);
    const int pos = atomicAdd(&cursor[col], 1);
    const int idx = offsets[col] + pos;
    rowbuf[idx] = row;
    valbuf[idx] = val;
}

// ---------------------------------------------------------------------------
// attn via MFMA: per (b, 64-node tile): loop h, P = q[64x64] x KV^T[64x64].
// A = q (bf16 in global, direct frag loads); B = KV [dv][dk] bf16 in LDS
// (parts summed + cvt while staging). denom via 64-thread VALU dots.
// Epilogue folds (inv*P + vsum)/denom * 0.25 into an output accumulator.
// ---------------------------------------------------------------------------
#define AKP 72   // LDS pitch for kvbf (144 B rows, 16B-aligned)
__global__ __launch_bounds__(256) void attn_mfma(
    const ushort* __restrict__ q16, const float* __restrict__ kv_p,
    const float* __restrict__ ksum_p, const float* __restrict__ vsum_p,
    const float* __restrict__ sumsq,
    const int* __restrict__ n_nodes, float* __restrict__ out)
{
    const int b = blockIdx.y;
    const int m0 = blockIdx.x * 64;
    const int t = threadIdx.x;
    const int l = t & 63, w = t >> 6;
    const int fr = l & 15, q4 = l >> 4;
    const int wn = (w & 1) * 32, wd = (w >> 1) * 32;

    __shared__ ushort kvbf[64 * AKP];
    __shared__ float ksum_l[64], vsum_l[64], denom_l[64];

    const float nn = (float)n_nodes[b];
    const float inv = 1.0f / (sqrtf(sumsq[0]) * sqrtf(sumsq[1]));
    f32x4 acco[2][2] = {};

    for (int h = 0; h < HH; ++h) {
        __syncthreads();   // prev h's MFMA reads done before restage
        {   // stage KV: sum 4 z-parts, cvt bf16; thread -> row dv=t>>2, 16 dk
            const int dv = t >> 2, dk0 = (t & 3) * 16;
            const float* kvg = &kv_p[(((size_t)b * HH + h) * 4) * 4096 + dv * 64 + dk0];
            float s[16];
#pragma unroll
            for (int c = 0; c < 4; ++c) {
                float4 p0 = *(const float4*)(kvg + 4 * c);
                float4 p1 = *(const float4*)(kvg + 4096 + 4 * c);
                float4 p2 = *(const float4*)(kvg + 8192 + 4 * c);
                float4 p3 = *(const float4*)(kvg + 12288 + 4 * c);
                s[4 * c + 0] = p0.x + p1.x + p2.x + p3.x;
                s[4 * c + 1] = p0.y + p1.y + p2.y + p3.y;
                s[4 * c + 2] = p0.z + p1.z + p2.z + p3.z;
                s[4 * c + 3] = p0.w + p1.w + p2.w + p3.w;
            }
            uint4 o0 = make_uint4(pkbf(s[0], s[1]), pkbf(s[2], s[3]),
                                  pkbf(s[4], s[5]), pkbf(s[6], s[7]));
            uint4 o1 = make_uint4(pkbf(s[8], s[9]), pkbf(s[10], s[11]),
                                  pkbf(s[12], s[13]), pkbf(s[14], s[15]));
            *(uint4*)&kvbf[dv * AKP + dk0] = o0;
            *(uint4*)&kvbf[dv * AKP + dk0 + 8] = o1;
        }
        if (t >= 64 && t < 128) {
            const int d = t - 64;
            const float* ksb = &ksum_p[(((size_t)b * HH + h) * 4) * 64];
            ksum_l[d] = ksb[d] + ksb[64 + d] + ksb[128 + d] + ksb[192 + d];
        } else if (t >= 128 && t < 192) {
            const int d = t - 128;
            const float* vsb = &vsum_p[(((size_t)b * HH + h) * 4) * 64];
            vsum_l[d] = vsb[d] + vsb[64 + d] + vsb[128 + d] + vsb[192 + d];
        }
        __syncthreads();

        if (t < 64) {   // denominators
            const ushort* qr = &q16[((size_t)(b * MM + m0 + t)) * HD + h * DD];
            float dsum = 0.f;
#pragma unroll
            for (int c = 0; c < 8; ++c) {
                u16x8 qq = *(const u16x8*)(qr + 8 * c);
#pragma unroll
                for (int j2 = 0; j2 < 8; ++j2)
                    dsum += bf2f(qq[j2]) * ksum_l[8 * c + j2];
            }
            denom_l[t] = nn + inv * dsum;
        }
        __syncthreads();

        f32x4 pacc[2][2] = {};
#pragma unroll
        for (int kx = 0; kx < 2; ++kx) {
            const int k0 = kx * 32;
            s16x8 af[2], bf[2];
#pragma unroll
            for (int il = 0; il < 2; ++il)
                af[il] = *(const s16x8*)&q16[
                    ((size_t)(b * MM + m0 + wn + 16 * il + fr)) * HD + h * DD + k0 + q4 * 8];
#pragma unroll
            for (int jl = 0; jl < 2; ++jl)
                bf[jl] = *(const s16x8*)&kvbf[(wd + 16 * jl + fr) * AKP + k0 + q4 * 8];
#pragma unroll
            for (int il = 0; il < 2; ++il)
#pragma unroll
                for (int jl = 0; jl < 2; ++jl)
                    pacc[il][jl] = __builtin_amdgcn_mfma_f32_16x16x32_bf16(
                        af[il], bf[jl], pacc[il][jl], 0, 0, 0);
        }
#pragma unroll
        for (int il = 0; il < 2; ++il)
#pragma unroll
            for (int m = 0; m < 4; ++m) {
                const float rden = 0.25f / denom_l[wn + 16 * il + q4 * 4 + m];
#pragma unroll
                for (int jl = 0; jl < 2; ++jl) {
                    const int d = wd + 16 * jl + fr;
                    acco[il][jl][m] += (inv * pacc[il][jl][m] + vsum_l[d]) * rden;
                }
            }
    }

#pragma unroll
    for (int il = 0; il < 2; ++il)
#pragma unroll
        for (int m = 0; m < 4; ++m) {
            const size_t node = (size_t)b * MM + m0 + wn + 16 * il + q4 * 4 + m;
#pragma unroll
            for (int jl = 0; jl < 2; ++jl)
                out[node * DD + wd + 16 * jl + fr] = acco[il][jl][m];
        }
}

// ---------------------------------------------------------------------------
// GCN gather: one wave per destination node; lane = feature. No atomics.
// ---------------------------------------------------------------------------
__global__ __launch_bounds__(256) void gcn_gather(
    const int* __restrict__ offsets, const int* __restrict__ rowbuf,
    const float* __restrict__ valbuf, const float* __restrict__ vbar,
    float* __restrict__ out)
{
    const int t = blockIdx.x * 256 + threadIdx.x;
    const int n = t >> 6, d = t & 63;
    const int s = offsets[n], e = offsets[n + 1];
    float acc = 0.f;
    int i = s;
    for (; i + 4 <= e; i += 4) {
        const int r0 = rowbuf[i], r1 = rowbuf[i + 1], r2 = rowbuf[i + 2], r3 = rowbuf[i + 3];
        const float w0 = valbuf[i], w1 = valbuf[i + 1], w2 = valbuf[i + 2], w3 = valbuf[i + 3];
        acc += w0 * vbar[(size_t)r0 * DD + d];
        acc += w1 * vbar[(size_t)r1 * DD + d];
        acc += w2 * vbar[(size_t)r2 * DD + d];
        acc += w3 * vbar[(size_t)r3 * DD + d];
    }
    for (; i < e; ++i)
        acc += valbuf[i] * vbar[(size_t)rowbuf[i] * DD + d];
    out[(size_t)n * DD + d] += acc;
}

// ---------------------------------------------------------------------------
extern "C" void kernel_launch(void* const* d_in, const int* in_sizes, int n_in,
                              void* d_out, int out_size, void* d_ws, size_t ws_size,
                              hipStream_t stream)
{
    (void)in_sizes; (void)n_in; (void)out_size; (void)ws_size;
    const float* Xq = (const float*)d_in[0];
    const float* Xs = (const float*)d_in[1];
    const float* ew = (const float*)d_in[2];
    const float* Wq = (const float*)d_in[3];
    const float* bq = (const float*)d_in[4];
    const float* Wk = (const float*)d_in[5];
    const float* bk = (const float*)d_in[6];
    const float* Wv = (const float*)d_in[7];
    const float* bv = (const float*)d_in[8];
    const int* n_nodes = (const int*)d_in[9];
    const int* ei = (const int*)d_in[10];
    float* out = (float*)d_out;
    float* ws  = (float*)d_ws;

    // workspace layout (float units); q/k/v are bf16 (half-float footprint)
    const size_t SZ_QKV  = (size_t)NN * HD / 2;        // 4194304 floats each
    const size_t OFF_Q    = 0;
    const size_t OFF_K    = SZ_QKV;
    const size_t OFF_V    = SZ_QKV * 2;
    const size_t OFF_SS   = SZ_QKV * 3;                // 16 floats
    const size_t OFF_DEG  = OFF_SS + 16;               // NN ints (zeroed)
    const size_t OFF_CUR  = OFF_DEG + NN;              // NN ints (zeroed)
    const size_t OFF_KV   = OFF_CUR + NN;              // BB*HH*4*4096 parts
    const size_t OFF_KSUM = OFF_KV + (size_t)BB * HH * 4 * 4096;
    const size_t OFF_VSUM = OFF_KSUM + (size_t)BB * HH * 4 * 64;
    const size_t OFF_OFFS = OFF_VSUM + (size_t)BB * HH * 4 * 64;  // NN+1
    const size_t OFF_ROWB = OFF_OFFS + NN + 16;        // EE ints
    const size_t OFF_VALB = OFF_ROWB + EE;             // EE floats
    const size_t OFF_VBAR = OFF_VALB + EE;             // NN*DD
    // total ≈ 81 MB

    ushort* q16   = (ushort*)(ws + OFF_Q);
    ushort* k16   = (ushort*)(ws + OFF_K);
    ushort* v16   = (ushort*)(ws + OFF_V);
    float* sumsq  = ws + OFF_SS;
    ushort* WT    = (ushort*)(ws + OFF_DEG);  // aliases deg/cursor: dead after gemm
    int*   deg    = (int*)(ws + OFF_DEG);
    int*   cursor = (int*)(ws + OFF_CUR);
    float* kv_p   = ws + OFF_KV;
    float* ksum_p = ws + OFF_KSUM;
    float* vsum_p = ws + OFF_VSUM;
    int*   offs   = (int*)(ws + OFF_OFFS);
    int*   rowbuf = (int*)(ws + OFF_ROWB);
    float* valbuf = ws + OFF_VALB;
    float* vbar   = ws + OFF_VBAR;

    hipMemsetAsync(sumsq, 0, 16 * sizeof(float), stream);
    convert_w<<<768, 256, 0, stream>>>(Wq, Wk, Wv, WT);
    qkv_gemm<<<1536, 256, 0, stream>>>(
        Xq, Xs, WT, bq, bk, bv, q16, k16, v16, sumsq);
    // WT dead; zero deg + cursor
    hipMemsetAsync(ws + OFF_DEG, 0, 2 * NN * sizeof(int), stream);
    deg_kernel<<<EE / 256, 256, 0, stream>>>(ei, deg);
    scan_kernel<<<1, 1024, 0, stream>>>(deg, offs);
    bucket_kernel<<<EE / 256, 256, 0, stream>>>(ei, ew, deg, offs, cursor, rowbuf, valbuf);
    kv_mfma<<<dim3(HH, BB, 4), 256, 0, stream>>>(k16, v16, kv_p, ksum_p, vsum_p);
    vbar_kernel<<<(NN * DD) / 256, 256, 0, stream>>>(v16, vbar);
    attn_mfma<<<dim3(MM / 64, BB), 256, 0, stream>>>(
        q16, kv_p, ksum_p, vsum_p, sumsq, n_nodes, out);
    gcn_gather<<<(NN * DD) / 256, 256, 0, stream>>>(offs, rowbuf, valbuf, vbar, out);
}

// Round 9
// 267.478 us; speedup vs baseline: 1.2404x; 1.2404x over previous
//
#include <hip/hip_runtime.h>
#include <hip/hip_bf16.h>

#define NN 32768   // nodes
#define BB 64      // graphs
#define MM 512     // nodes per graph
#define HH 4       // heads
#define DD 64      // head dim
#define INF 256    // input features
#define HD 256     // H*D
#define EE 524288  // edges

typedef unsigned short ushort;
typedef unsigned int uint;
typedef short s16x8 __attribute__((ext_vector_type(8)));
typedef ushort u16x8 __attribute__((ext_vector_type(8)));
typedef float f32x4 __attribute__((ext_vector_type(4)));

__device__ __forceinline__ ushort f2bf(float f) {
    uint u = __float_as_uint(f);
    return (ushort)((u + 0x7fffu + ((u >> 16) & 1u)) >> 16);
}
__device__ __forceinline__ float bf2f(ushort u) {
    return __uint_as_float((uint)u << 16);
}
__device__ __forceinline__ uint pkbf(float x, float y) {
    __hip_bfloat162 h = __float22bfloat162_rn(make_float2(x, y));
    return *(uint*)&h;
}

// ---------------------------------------------------------------------------
// K1: convert_w (blocks 0..767) ∪ deg histogram (blocks 768..2815).
// ---------------------------------------------------------------------------
__global__ __launch_bounds__(256) void prep_kernel(
    const float* __restrict__ Wq, const float* __restrict__ Wk,
    const float* __restrict__ Wv, ushort* __restrict__ WT,
    const int* __restrict__ ei, int* __restrict__ deg)
{
    const int bid = blockIdx.x;
    if (bid < 768) {
        const int id = bid * 256 + threadIdx.x;      // 3*65536
        const int mat = id >> 16, rem = id & 65535;
        const int n = rem >> 8, kk = rem & 255;
        const float* W = (mat == 0) ? Wq : (mat == 1) ? Wk : Wv;
        WT[id] = f2bf(W[kk * 256 + n]);              // WT[mat][n][kk]
    } else {
        const int e = (bid - 768) * 256 + threadIdx.x;   // EE total
        atomicAdd(&deg[ei[EE + e]], 1);
    }
}

// ---------------------------------------------------------------------------
// K2: qkv GEMM (blocks 0..1535, round-7 structure: LDS-staged, register
// double-buffered K-loop, slim bf16 epilogue) ∪ scan (block 1536).
// ---------------------------------------------------------------------------
#define BKP 40
#define BPI 32
__global__ __launch_bounds__(256) void qkv_scan(
    const float* __restrict__ Xq, const float* __restrict__ Xs,
    const ushort* __restrict__ WT,
    const float* __restrict__ bq, const float* __restrict__ bk,
    const float* __restrict__ bv,
    ushort* __restrict__ qo, ushort* __restrict__ ko, ushort* __restrict__ vo,
    float* __restrict__ sumsq,
    const int* __restrict__ deg, int* __restrict__ offsets)
{
    __shared__ ushort Asu[128 * BKP];
    __shared__ ushort Bsu[128 * BPI];
    __shared__ float wred[4];
    __shared__ int part[256];

    const int id = blockIdx.x;
    const int t = threadIdx.x;

    if (id == 1536) {   // exclusive scan of deg -> offsets, 128 elems/thread
        const int base = t * 128;
        int s = 0;
        for (int i = 0; i < 128; ++i) s += deg[base + i];
        part[t] = s;
        __syncthreads();
        for (int off = 1; off < 256; off <<= 1) {
            int a = part[t];
            int b2 = (t >= off) ? part[t - off] : 0;
            __syncthreads();
            part[t] = a + b2;
            __syncthreads();
        }
        int run = (t == 0) ? 0 : part[t - 1];
        for (int i = 0; i < 128; ++i) { offsets[base + i] = run; run += deg[base + i]; }
        if (t == 255) offsets[NN] = run;
        return;
    }

    const int vv = (id & 7) * 192 + (id >> 3);   // XCD-contiguous row-groups
    const int rt = vv / 6, ct = vv % 6;
    const int wsel = ct >> 1;                    // 0:q 1:k 2:v
    const float* A    = (wsel == 0) ? Xq : Xs;
    const ushort* W   = WT + (size_t)wsel * 65536;
    const float* bias = (wsel == 0) ? bq : (wsel == 1) ? bk : bv;
    ushort* C         = (wsel == 0) ? qo : (wsel == 1) ? ko : vo;
    const int row0 = rt * 128;
    const int col0 = (ct & 1) * 128;

    const int l = t & 63, w = t >> 6;
    const int fr = l & 15, q4 = l >> 4;
    const int wr = (w & 1) * 64, wc = (w >> 1) * 64;
    const int sr = t >> 1, sh = (t & 1) * 16;

    f32x4 acc[4][4] = {};

    float4 a0, a1, a2, a3;
    u16x8 b0, b1;
    {
        const float* ap = &A[(size_t)(row0 + sr) * INF + sh];
        a0 = *(const float4*)(ap + 0);
        a1 = *(const float4*)(ap + 4);
        a2 = *(const float4*)(ap + 8);
        a3 = *(const float4*)(ap + 12);
        const ushort* bp = &W[(size_t)(col0 + sr) * INF + sh];
        b0 = *(const u16x8*)(bp + 0);
        b1 = *(const u16x8*)(bp + 8);
    }

    for (int it = 0; it < 8; ++it) {
        __syncthreads();
        {
            u16x8 pa0, pa1;
            pa0[0] = f2bf(a0.x); pa0[1] = f2bf(a0.y); pa0[2] = f2bf(a0.z); pa0[3] = f2bf(a0.w);
            pa0[4] = f2bf(a1.x); pa0[5] = f2bf(a1.y); pa0[6] = f2bf(a1.z); pa0[7] = f2bf(a1.w);
            pa1[0] = f2bf(a2.x); pa1[1] = f2bf(a2.y); pa1[2] = f2bf(a2.z); pa1[3] = f2bf(a2.w);
            pa1[4] = f2bf(a3.x); pa1[5] = f2bf(a3.y); pa1[6] = f2bf(a3.z); pa1[7] = f2bf(a3.w);
            *(u16x8*)&Asu[sr * BKP + sh] = pa0;
            *(u16x8*)&Asu[sr * BKP + sh + 8] = pa1;
            *(u16x8*)&Bsu[sr * BPI + sh] = b0;
            *(u16x8*)&Bsu[sr * BPI + sh + 8] = b1;
        }
        __syncthreads();

        if (it < 7) {
            const int k0 = (it + 1) * 32;
            const float* ap = &A[(size_t)(row0 + sr) * INF + k0 + sh];
            a0 = *(const float4*)(ap + 0);
            a1 = *(const float4*)(ap + 4);
            a2 = *(const float4*)(ap + 8);
            a3 = *(const float4*)(ap + 12);
            const ushort* bp = &W[(size_t)(col0 + sr) * INF + k0 + sh];
            b0 = *(const u16x8*)(bp + 0);
            b1 = *(const u16x8*)(bp + 8);
        }

        const int kg = q4 * 8;
        s16x8 af[4], bf[4];
#pragma unroll
        for (int i = 0; i < 4; ++i)
            af[i] = *(const s16x8*)&Asu[(wr + i * 16 + fr) * BKP + kg];
#pragma unroll
        for (int j = 0; j < 4; ++j)
            bf[j] = *(const s16x8*)&Bsu[(wc + j * 16 + fr) * BPI + kg];
#pragma unroll
        for (int i = 0; i < 4; ++i)
#pragma unroll
            for (int j = 0; j < 4; ++j)
                acc[i][j] = __builtin_amdgcn_mfma_f32_16x16x32_bf16(
                    af[i], bf[j], acc[i][j], 0, 0, 0);
    }

    float loc = 0.f;
#pragma unroll
    for (int j = 0; j < 4; ++j) {
        const int colg = col0 + wc + j * 16 + fr;
        const float bj = bias[colg];
#pragma unroll
        for (int i = 0; i < 4; ++i) {
            const int rowg = row0 + wr + i * 16 + q4 * 4;
#pragma unroll
            for (int m = 0; m < 4; ++m) {
                float cv = acc[i][j][m] + bj;
                loc += cv * cv;
                C[(size_t)(rowg + m) * HD + colg] = f2bf(cv);
            }
        }
    }
    if (wsel < 2) {
#pragma unroll
        for (int off = 32; off > 0; off >>= 1) loc += __shfl_down(loc, off, 64);
        if (l == 0) wred[w] = loc;
        __syncthreads();
        if (t == 0) atomicAdd(&sumsq[wsel], wred[0] + wred[1] + wred[2] + wred[3]);
    }
}

// ---------------------------------------------------------------------------
// K3: kv_mfma (blocks 0..1023) ∪ vbar (blocks 1024..3071, 4 elems/thread).
// kv parts stored transposed [dv][dk] for attn's B-operand layout.
// ---------------------------------------------------------------------------
#define KVP 136
__global__ __launch_bounds__(256) void kv_vbar(
    const ushort* __restrict__ k16, const ushort* __restrict__ v16,
    float* __restrict__ kv_p, float* __restrict__ ksum_p, float* __restrict__ vsum_p,
    float* __restrict__ vbar)
{
    __shared__ ushort kT[64 * KVP];
    __shared__ ushort vT[64 * KVP];
    const int bid = blockIdx.x;
    const int t = threadIdx.x;

    if (bid >= 1024) {   // vbar: mean over heads
        const int idx = (bid - 1024) * 1024 + t * 4;
        const int n = idx >> 6, d0 = idx & 63;
        const ushort* vr = &v16[(size_t)n * HD + d0];
        float4 o;
        float* op = (float*)&o;
#pragma unroll
        for (int j = 0; j < 4; ++j)
            op[j] = 0.25f * (bf2f(vr[j]) + bf2f(vr[64 + j]) +
                             bf2f(vr[128 + j]) + bf2f(vr[192 + j]));
        *(float4*)&vbar[idx] = o;
        return;
    }

    const int h = bid & 3, b = (bid >> 2) & 63, z = bid >> 8;
    const int l = t & 63, w = t >> 6;
    const size_t base = (size_t)b * MM * HD + (size_t)h * DD;
    const int m0 = z * 128;

    {
        const int mat = t >> 7;
        const int u = t & 63;
        const int dhalf = (t >> 6) & 1;
        const int r0 = 2 * u;
        const int d0 = dhalf * 32;
        const ushort* src = mat ? v16 : k16;
        ushort* dst = mat ? vT : kT;
        const ushort* p0 = &src[base + (size_t)(m0 + r0) * HD + d0];
        const ushort* p1 = p0 + HD;
        u16x8 ra[4], rb[4];
#pragma unroll
        for (int i = 0; i < 4; ++i) ra[i] = *(const u16x8*)(p0 + 8 * i);
#pragma unroll
        for (int i = 0; i < 4; ++i) rb[i] = *(const u16x8*)(p1 + 8 * i);
#pragma unroll
        for (int i = 0; i < 4; ++i)
#pragma unroll
            for (int jj = 0; jj < 8; ++jj) {
                const int d = d0 + 8 * i + jj;
                uint pk = (uint)ra[i][jj] | ((uint)rb[i][jj] << 16);
                *(uint*)&dst[d * KVP + r0] = pk;
            }
    }
    __syncthreads();

    const int fr = l & 15, q4 = l >> 4, kg = q4 * 8;
    const int wr2 = (w & 1) * 32, wc2 = (w >> 1) * 32;
    s16x8 ones;
#pragma unroll
    for (int i = 0; i < 8; ++i) ones[i] = (short)0x3F80;

    f32x4 acc[2][2] = {};
    f32x4 aks[2] = {};
    f32x4 avs[2] = {};
#pragma unroll
    for (int s = 0; s < 4; ++s) {
        const int mo = s * 32 + kg;
        s16x8 af[2], bf[2];
        af[0] = *(const s16x8*)&kT[(wr2 + fr) * KVP + mo];
        af[1] = *(const s16x8*)&kT[(wr2 + 16 + fr) * KVP + mo];
        bf[0] = *(const s16x8*)&vT[(wc2 + fr) * KVP + mo];
        bf[1] = *(const s16x8*)&vT[(wc2 + 16 + fr) * KVP + mo];
#pragma unroll
        for (int il = 0; il < 2; ++il)
#pragma unroll
            for (int jl = 0; jl < 2; ++jl)
                acc[il][jl] = __builtin_amdgcn_mfma_f32_16x16x32_bf16(
                    af[il], bf[jl], acc[il][jl], 0, 0, 0);
#pragma unroll
        for (int il = 0; il < 2; ++il)
            aks[il] = __builtin_amdgcn_mfma_f32_16x16x32_bf16(
                af[il], ones, aks[il], 0, 0, 0);
#pragma unroll
        for (int jl = 0; jl < 2; ++jl)
            avs[jl] = __builtin_amdgcn_mfma_f32_16x16x32_bf16(
                ones, bf[jl], avs[jl], 0, 0, 0);
    }

    float* kvb = &kv_p[(((size_t)b * HH + h) * 4 + z) * 4096];
#pragma unroll
    for (int jl = 0; jl < 2; ++jl) {
        const int dv = wc2 + 16 * jl + fr;
#pragma unroll
        for (int il = 0; il < 2; ++il) {
            const int dk = wr2 + 16 * il + q4 * 4;
            *(f32x4*)&kvb[(size_t)dv * 64 + dk] = acc[il][jl];
        }
    }
    float* ksb = &ksum_p[(((size_t)b * HH + h) * 4 + z) * 64];
    float* vsb = &vsum_p[(((size_t)b * HH + h) * 4 + z) * 64];
    if (wc2 == 0 && fr == 0) {
#pragma unroll
        for (int il = 0; il < 2; ++il)
#pragma unroll
            for (int m = 0; m < 4; ++m)
                ksb[wr2 + 16 * il + q4 * 4 + m] = aks[il][m];
    }
    if (wr2 == 0 && l < 16) {
        vsb[wc2 + l]      = avs[0][0];
        vsb[wc2 + 16 + l] = avs[1][0];
    }
}

// ---------------------------------------------------------------------------
// K4: kv_red (blocks 0..1023: sum 4 z-parts -> bf16 kv16) ∪ sumred (blocks
// 1024..1151: ksum/vsum finals) ∪ bucket (blocks 1152..3199: CSR fill,
// packed int2 {row, val}).
// ---------------------------------------------------------------------------
__global__ __launch_bounds__(256) void red_bucket(
    const float* __restrict__ kv_p, const float* __restrict__ ksum_p,
    const float* __restrict__ vsum_p,
    ushort* __restrict__ kv16, float* __restrict__ ksum_f, float* __restrict__ vsum_f,
    const int* __restrict__ ei, const float* __restrict__ ew,
    const int* __restrict__ deg, const int* __restrict__ offsets,
    int* __restrict__ cursor, int2* __restrict__ pairbuf)
{
    const int bid = blockIdx.x;
    const int t = threadIdx.x;

    if (bid < 1024) {          // kv_red: 4 outputs/thread
        const int o4 = bid * 1024 + t * 4;
        const int bh = o4 >> 12, off = o4 & 4095;
        const float* p = &kv_p[(size_t)bh * 16384 + off];
        float4 s0 = *(const float4*)p;
        float4 s1 = *(const float4*)(p + 4096);
        float4 s2 = *(const float4*)(p + 8192);
        float4 s3 = *(const float4*)(p + 12288);
        const float r0 = s0.x + s1.x + s2.x + s3.x;
        const float r1 = s0.y + s1.y + s2.y + s3.y;
        const float r2 = s0.z + s1.z + s2.z + s3.z;
        const float r3 = s0.w + s1.w + s2.w + s3.w;
        uint2 pk = make_uint2(pkbf(r0, r1), pkbf(r2, r3));
        *(uint2*)&kv16[(size_t)bh * 4096 + off] = pk;
    } else if (bid < 1152) {   // ksum/vsum reduce
        const int o = (bid - 1024) * 256 + t;    // 0..32767
        const float* src = (o < 16384) ? ksum_p : vsum_p;
        float* dst = (o < 16384) ? ksum_f : vsum_f;
        const int oo = o & 16383;
        const int bh = oo >> 6, d = oo & 63;
        const float* p = &src[(size_t)bh * 256 + d];
        dst[oo] = p[0] + p[64] + p[128] + p[192];
    } else {                   // bucket
        const int e = (bid - 1152) * 256 + t;
        const int row = ei[e], col = ei[EE + e];
        const long long prod = (long long)deg[row] * (long long)deg[col];
        float val = 0.f;
        if (prod > 0) val = ew[e] * __frsqrt_rn((float)prod);
        const int pos = atomicAdd(&cursor[col], 1);
        pairbuf[offsets[col] + pos] = make_int2(row, __float_as_int(val));
    }
}

// ---------------------------------------------------------------------------
// K5: attn via MFMA. P = q[64x64] x KV^T; KV staged bf16 from kv16.
// ---------------------------------------------------------------------------
#define AKP 72
__global__ __launch_bounds__(256) void attn_mfma(
    const ushort* __restrict__ q16, const ushort* __restrict__ kv16,
    const float* __restrict__ ksum_f, const float* __restrict__ vsum_f,
    const float* __restrict__ sumsq,
    const int* __restrict__ n_nodes, float* __restrict__ out)
{
    const int b = blockIdx.y;
    const int m0 = blockIdx.x * 64;
    const int t = threadIdx.x;
    const int l = t & 63, w = t >> 6;
    const int fr = l & 15, q4 = l >> 4;
    const int wn = (w & 1) * 32, wd = (w >> 1) * 32;

    __shared__ ushort kvbf[64 * AKP];
    __shared__ float ksum_l[64], vsum_l[64], denom_l[64];

    const float nn = (float)n_nodes[b];
    const float inv = 1.0f / (sqrtf(sumsq[0]) * sqrtf(sumsq[1]));
    f32x4 acco[2][2] = {};

    for (int h = 0; h < HH; ++h) {
        __syncthreads();
        {   // stage bf16 KV [dv][dk]
            const int dv = t >> 2, dk0 = (t & 3) * 16;
            const ushort* kvg = &kv16[((size_t)(b * HH + h)) * 4096 + dv * 64 + dk0];
            *(uint4*)&kvbf[dv * AKP + dk0]     = *(const uint4*)kvg;
            *(uint4*)&kvbf[dv * AKP + dk0 + 8] = *(const uint4*)(kvg + 8);
        }
        if (t >= 64 && t < 128)
            ksum_l[t - 64] = ksum_f[((size_t)(b * HH + h)) * 64 + t - 64];
        else if (t >= 128 && t < 192)
            vsum_l[t - 128] = vsum_f[((size_t)(b * HH + h)) * 64 + t - 128];
        __syncthreads();

        if (t < 64) {   // denominators
            const ushort* qr = &q16[((size_t)(b * MM + m0 + t)) * HD + h * DD];
            float dsum = 0.f;
#pragma unroll
            for (int c = 0; c < 8; ++c) {
                u16x8 qq = *(const u16x8*)(qr + 8 * c);
#pragma unroll
                for (int j2 = 0; j2 < 8; ++j2)
                    dsum += bf2f(qq[j2]) * ksum_l[8 * c + j2];
            }
            denom_l[t] = nn + inv * dsum;
        }
        __syncthreads();

        f32x4 pacc[2][2] = {};
#pragma unroll
        for (int kx = 0; kx < 2; ++kx) {
            const int k0 = kx * 32;
            s16x8 af[2], bf[2];
#pragma unroll
            for (int il = 0; il < 2; ++il)
                af[il] = *(const s16x8*)&q16[
                    ((size_t)(b * MM + m0 + wn + 16 * il + fr)) * HD + h * DD + k0 + q4 * 8];
#pragma unroll
            for (int jl = 0; jl < 2; ++jl)
                bf[jl] = *(const s16x8*)&kvbf[(wd + 16 * jl + fr) * AKP + k0 + q4 * 8];
#pragma unroll
            for (int il = 0; il < 2; ++il)
#pragma unroll
                for (int jl = 0; jl < 2; ++jl)
                    pacc[il][jl] = __builtin_amdgcn_mfma_f32_16x16x32_bf16(
                        af[il], bf[jl], pacc[il][jl], 0, 0, 0);
        }
#pragma unroll
        for (int il = 0; il < 2; ++il)
#pragma unroll
            for (int m = 0; m < 4; ++m) {
                const float rden = 0.25f / denom_l[wn + 16 * il + q4 * 4 + m];
#pragma unroll
                for (int jl = 0; jl < 2; ++jl) {
                    const int d = wd + 16 * jl + fr;
                    acco[il][jl][m] += (inv * pacc[il][jl][m] + vsum_l[d]) * rden;
                }
            }
    }

#pragma unroll
    for (int il = 0; il < 2; ++il)
#pragma unroll
        for (int m = 0; m < 4; ++m) {
            const size_t node = (size_t)b * MM + m0 + wn + 16 * il + q4 * 4 + m;
#pragma unroll
            for (int jl = 0; jl < 2; ++jl)
                out[node * DD + wd + 16 * jl + fr] = acco[il][jl][m];
        }
}

// ---------------------------------------------------------------------------
// K6: GCN gather (packed pairbuf). out[n] += sum val*vbar[row]. No atomics.
// ---------------------------------------------------------------------------
__global__ __launch_bounds__(256) void gcn_gather(
    const int* __restrict__ offsets, const int2* __restrict__ pairbuf,
    const float* __restrict__ vbar, float* __restrict__ out)
{
    const int t = blockIdx.x * 256 + threadIdx.x;
    const int n = t >> 6, d = t & 63;
    const int s = offsets[n], e = offsets[n + 1];
    float acc = 0.f;
    int i = s;
    for (; i + 4 <= e; i += 4) {
        const int2 p0 = pairbuf[i],     p1 = pairbuf[i + 1];
        const int2 p2 = pairbuf[i + 2], p3 = pairbuf[i + 3];
        acc += __int_as_float(p0.y) * vbar[(size_t)p0.x * DD + d];
        acc += __int_as_float(p1.y) * vbar[(size_t)p1.x * DD + d];
        acc += __int_as_float(p2.y) * vbar[(size_t)p2.x * DD + d];
        acc += __int_as_float(p3.y) * vbar[(size_t)p3.x * DD + d];
    }
    for (; i < e; ++i) {
        const int2 p = pairbuf[i];
        acc += __int_as_float(p.y) * vbar[(size_t)p.x * DD + d];
    }
    out[(size_t)n * DD + d] += acc;
}

// ---------------------------------------------------------------------------
extern "C" void kernel_launch(void* const* d_in, const int* in_sizes, int n_in,
                              void* d_out, int out_size, void* d_ws, size_t ws_size,
                              hipStream_t stream)
{
    (void)in_sizes; (void)n_in; (void)out_size; (void)ws_size;
    const float* Xq = (const float*)d_in[0];
    const float* Xs = (const float*)d_in[1];
    const float* ew = (const float*)d_in[2];
    const float* Wq = (const float*)d_in[3];
    const float* bq = (const float*)d_in[4];
    const float* Wk = (const float*)d_in[5];
    const float* bk = (const float*)d_in[6];
    const float* Wv = (const float*)d_in[7];
    const float* bv = (const float*)d_in[8];
    const int* n_nodes = (const int*)d_in[9];
    const int* ei = (const int*)d_in[10];
    float* out = (float*)d_out;
    float* ws  = (float*)d_ws;

    // workspace layout (float units); q/k/v bf16
    const size_t SZ_QKV   = (size_t)NN * HD / 2;       // 4194304 each
    const size_t OFF_Q    = 0;
    const size_t OFF_K    = SZ_QKV;
    const size_t OFF_V    = SZ_QKV * 2;
    const size_t OFF_SS   = SZ_QKV * 3;                // 16 floats (zeroed)
    const size_t OFF_DEG  = OFF_SS + 16;               // NN ints (zeroed)
    const size_t OFF_CUR  = OFF_DEG + NN;              // NN ints (zeroed)
    const size_t OFF_WT   = OFF_CUR + NN;              // 3*65536 ushorts
    const size_t OFF_KV   = OFF_WT + 3 * 65536 / 2;    // BB*HH*4*4096 parts
    const size_t OFF_KSP  = OFF_KV + (size_t)BB * HH * 4 * 4096;
    const size_t OFF_VSP  = OFF_KSP + (size_t)BB * HH * 4 * 64;
    const size_t OFF_KV16 = OFF_VSP + (size_t)BB * HH * 4 * 64;   // bf16 1M
    const size_t OFF_KSF  = OFF_KV16 + (size_t)BB * HH * 4096 / 2;
    const size_t OFF_VSF  = OFF_KSF + (size_t)BB * HH * 64;
    const size_t OFF_OFFS = OFF_VSF + (size_t)BB * HH * 64;       // NN+1
    const size_t OFF_PAIR = OFF_OFFS + NN + 16;        // EE int2
    const size_t OFF_VBAR = OFF_PAIR + 2 * (size_t)EE; // NN*DD
    // total ≈ 90 MB

    ushort* q16   = (ushort*)(ws + OFF_Q);
    ushort* k16   = (ushort*)(ws + OFF_K);
    ushort* v16   = (ushort*)(ws + OFF_V);
    float* sumsq  = ws + OFF_SS;
    int*   deg    = (int*)(ws + OFF_DEG);
    int*   cursor = (int*)(ws + OFF_CUR);
    ushort* WT    = (ushort*)(ws + OFF_WT);
    float* kv_p   = ws + OFF_KV;
    float* ksum_p = ws + OFF_KSP;
    float* vsum_p = ws + OFF_VSP;
    ushort* kv16  = (ushort*)(ws + OFF_KV16);
    float* ksum_f = ws + OFF_KSF;
    float* vsum_f = ws + OFF_VSF;
    int*   offs   = (int*)(ws + OFF_OFFS);
    int2*  pairb  = (int2*)(ws + OFF_PAIR);
    float* vbar   = ws + OFF_VBAR;

    // zero sumsq + deg + cursor (contiguous)
    hipMemsetAsync(sumsq, 0, (16 + 2 * NN) * sizeof(float), stream);
    prep_kernel<<<2816, 256, 0, stream>>>(Wq, Wk, Wv, WT, ei, deg);
    qkv_scan<<<1537, 256, 0, stream>>>(
        Xq, Xs, WT, bq, bk, bv, q16, k16, v16, sumsq, deg, offs);
    kv_vbar<<<3072, 256, 0, stream>>>(k16, v16, kv_p, ksum_p, vsum_p, vbar);
    red_bucket<<<3200, 256, 0, stream>>>(
        kv_p, ksum_p, vsum_p, kv16, ksum_f, vsum_f,
        ei, ew, deg, offs, cursor, pairb);
    attn_mfma<<<dim3(MM / 64, BB), 256, 0, stream>>>(
        q16, kv16, ksum_f, vsum_f, sumsq, n_nodes, out);
    gcn_gather<<<(NN * DD) / 256, 256, 0, stream>>>(offs, pairb, vbar, out);
}